// Round 5
// baseline (517.448 us; speedup 1.0000x reference)
//
#include <hip/hip_runtime.h>
#include <math.h>

// Problem constants
#define BB 32
#define CC 256
#define HH 64
#define WW 64
#define NN 4096   // H*W

// k_gram tile geometry
#define KSTEP 32
#define SROW  140   // LDS row stride (floats): 128 cols + 4-float gap per 32 + pad

__inline__ __device__ float waveReduceSum(float v) {
    #pragma unroll
    for (int off = 32; off > 0; off >>= 1) v += __shfl_xor(v, off);
    return v;
}
__inline__ __device__ float waveReduceMax(float v) {
    #pragma unroll
    for (int off = 32; off > 0; off >>= 1) v = fmaxf(v, __shfl_xor(v, off));
    return v;
}

// ---------------------------------------------------------------------------
// Kernel 1: per-(b,c) plane prep (unchanged — passed exact twice).
// ---------------------------------------------------------------------------
__global__ __launch_bounds__(256) void k_prep(const float* __restrict__ F,
                                              float* __restrict__ inv_norm,
                                              float* __restrict__ s_score) {
    const int plane = blockIdx.x;                 // b*256 + c
    const int tid = threadIdx.x;
    __shared__ float bin[4096];
    __shared__ float rowsum[4096];
    __shared__ float swS[4], swQ[4], swM[4];

    const float4* src = (const float4*)(F + (size_t)plane * NN);
    float4 v[4];
    float sum = 0.f, ssq = 0.f, mx = -INFINITY;
    #pragma unroll
    for (int q = 0; q < 4; ++q) {
        v[q] = src[tid + q * 256];
        sum += v[q].x + v[q].y + v[q].z + v[q].w;
        ssq += v[q].x * v[q].x + v[q].y * v[q].y + v[q].z * v[q].z + v[q].w * v[q].w;
        mx = fmaxf(mx, fmaxf(fmaxf(v[q].x, v[q].y), fmaxf(v[q].z, v[q].w)));
    }
    sum = waveReduceSum(sum);
    ssq = waveReduceSum(ssq);
    mx  = waveReduceMax(mx);
    const int w = tid >> 6, ln = tid & 63;
    if (ln == 0) { swS[w] = sum; swQ[w] = ssq; swM[w] = mx; }
    __syncthreads();
    if (tid == 0) {
        swS[0] = swS[0] + swS[1] + swS[2] + swS[3];
        swQ[0] = swQ[0] + swQ[1] + swQ[2] + swQ[3];
        swM[0] = fmaxf(fmaxf(swM[0], swM[1]), fmaxf(swM[2], swM[3]));
    }
    __syncthreads();
    const float totsum = swS[0];
    const float totssq = swQ[0];
    const float thr = 0.6f * swM[0];

    #pragma unroll
    for (int q = 0; q < 4; ++q) {
        const int base = (tid + q * 256) * 4;
        bin[base + 0] = (v[q].x >= thr) ? 1.f : 0.f;
        bin[base + 1] = (v[q].y >= thr) ? 1.f : 0.f;
        bin[base + 2] = (v[q].z >= thr) ? 1.f : 0.f;
        bin[base + 3] = (v[q].w >= thr) ? 1.f : 0.f;
    }
    __syncthreads();

    #pragma unroll
    for (int q = 0; q < 16; ++q) {
        const int p = tid + q * 256;
        const int h = p >> 6, x = p & 63;
        float s5 = 0.f;
        #pragma unroll
        for (int dw = -2; dw <= 2; ++dw) {
            const int xx = x + dw;
            if (xx >= 0 && xx < 64) s5 += bin[h * 64 + xx];
        }
        rowsum[p] = s5;
    }
    __syncthreads();

    int cge = 0;
    #pragma unroll
    for (int q = 0; q < 16; ++q) {
        const int p = tid + q * 256;
        const int h = p >> 6, x = p & 63;
        float cnt = 0.f;
        #pragma unroll
        for (int dh = -2; dh <= 2; ++dh) {
            const int hh = h + dh;
            if (hh >= 0 && hh < 64) cnt += rowsum[hh * 64 + x];
        }
        if (cnt >= 12.5f) cge++;   // density >= 0.5 exactly (integer counts)
    }
    float cf = waveReduceSum((float)cge);
    __syncthreads();
    if (ln == 0) swS[w] = cf;
    __syncthreads();
    if (tid == 0) {
        const float total = swS[0] + swS[1] + swS[2] + swS[3];
        const float d = total / 4096.f;
        const float a = 1.f / (1.f + expf(-(totsum / 4096.f)));
        s_score[plane] = sqrtf(a) * sqrtf(d);
        inv_norm[plane] = 1.f / (sqrtf(totssq) + 1e-6f);
    }
}

// ---------------------------------------------------------------------------
// Kernel 2: gram partials, 128x128 tiles, 8x8 microtile, split-K x nch.
// Symmetric tile set t in {0:(0,0), 1:(0,1), 2:(1,1)} over 128-row halves.
// LDS col remap col' = col + (col>>5)*4 (row stride 140):
//   staging writes 2-way (free), A-frag reads broadcast, B-frag reads
//   hit the 2-round minimum -> near-zero bank conflicts.
// Row-norm scaling applied at epilogue (exact product scaling).
// Output: S_part[bc*3 + t][128][128] f32, bc in [0, 32*nch).
// ---------------------------------------------------------------------------
__global__ __launch_bounds__(256) void k_gram(const float* __restrict__ F,
                                              const float* __restrict__ inv_norm,
                                              float* __restrict__ S_part,
                                              int csh) {
    const int t  = blockIdx.x;       // 0..2
    const int bc = blockIdx.y;       // 0..32*nch-1
    const int b = bc >> csh, chunk = bc & ((1 << csh) - 1);
    const int k0 = chunk << (12 - csh);            // chunk * (4096>>csh)
    const int iters = (4096 >> csh) / KSTEP;
    const int IA = (t == 2) ? 1 : 0;
    const int JB = (t == 0) ? 0 : 1;

    __shared__ float As[KSTEP * SROW];
    __shared__ float Bs[KSTEP * SROW];

    const int tid = threadIdx.x;
    const int u = tid & 7;           // float4 slot within 32-float k-window
    const int rbase = tid >> 3;      // 0..31

    const float* FA = F + (size_t)b * CC * NN + (size_t)(IA * 128) * NN;
    const float* FB = F + (size_t)b * CC * NN + (size_t)(JB * 128) * NN;

    const int r0 = (tid >> 4) << 3;  // 0..120 step 8
    const int c0 = (tid & 15) << 3;  // 0..120 step 8
    const int cA = r0 + ((r0 >> 5) << 2);
    const int cB = c0 + ((c0 >> 5) << 2);

    float acc[64];
    #pragma unroll
    for (int e = 0; e < 64; ++e) acc[e] = 0.f;

    float4 stA[4], stB[4];
    {   // preload s = 0
        #pragma unroll
        for (int p = 0; p < 4; ++p) {
            const int row = p * 32 + rbase;
            stA[p] = *(const float4*)(FA + (size_t)row * NN + k0 + u * 4);
            stB[p] = *(const float4*)(FB + (size_t)row * NN + k0 + u * 4);
        }
    }

    for (int s = 0; s < iters; ++s) {
        __syncthreads();             // LDS free from previous compute
        #pragma unroll
        for (int p = 0; p < 4; ++p) {
            const int row = p * 32 + rbase;
            const int col = row + ((row >> 5) << 2);
            const float* va = (const float*)&stA[p];
            const float* vb = (const float*)&stB[p];
            #pragma unroll
            for (int j = 0; j < 4; ++j) {
                As[(u * 4 + j) * SROW + col] = va[j];
                Bs[(u * 4 + j) * SROW + col] = vb[j];
            }
        }
        __syncthreads();
        if (s + 1 < iters) {         // prefetch next k-window (overlaps compute)
            const int kw = k0 + (s + 1) * KSTEP;
            #pragma unroll
            for (int p = 0; p < 4; ++p) {
                const int row = p * 32 + rbase;
                stA[p] = *(const float4*)(FA + (size_t)row * NN + kw + u * 4);
                stB[p] = *(const float4*)(FB + (size_t)row * NN + kw + u * 4);
            }
        }
        #pragma unroll
        for (int kk = 0; kk < KSTEP; ++kk) {
            const float4 a0 = *(const float4*)(As + kk * SROW + cA);
            const float4 a1 = *(const float4*)(As + kk * SROW + cA + 4);
            const float4 b0 = *(const float4*)(Bs + kk * SROW + cB);
            const float4 b1 = *(const float4*)(Bs + kk * SROW + cB + 4);
            const float ar[8] = {a0.x,a0.y,a0.z,a0.w,a1.x,a1.y,a1.z,a1.w};
            const float br[8] = {b0.x,b0.y,b0.z,b0.w,b1.x,b1.y,b1.z,b1.w};
            #pragma unroll
            for (int rr = 0; rr < 8; ++rr)
                #pragma unroll
                for (int cc = 0; cc < 8; ++cc)
                    acc[rr * 8 + cc] = fmaf(ar[rr], br[cc], acc[rr * 8 + cc]);
        }
    }

    // epilogue: scale by row norms, store
    const float* invA = inv_norm + b * CC + IA * 128;
    const float* invB = inv_norm + b * CC + JB * 128;
    float sA[8], sB[8];
    #pragma unroll
    for (int e = 0; e < 8; ++e) { sA[e] = invA[r0 + e]; sB[e] = invB[c0 + e]; }
    float* dst = S_part + ((size_t)bc * 3 + t) * 16384;
    #pragma unroll
    for (int rr = 0; rr < 8; ++rr)
        #pragma unroll
        for (int cc = 0; cc < 8; ++cc)
            dst[(r0 + rr) * 128 + (c0 + cc)] = acc[rr * 8 + cc] * sA[rr] * sB[cc];
}

// ---------------------------------------------------------------------------
// Kernel 3: reduce npart partials (f64, deterministic), EMA, symmetrize.
// Tile map for (c,d), d>=c: t = (c>>7) + (d>>7).
// ---------------------------------------------------------------------------
__global__ __launch_bounds__(256) void k_snew(const float* __restrict__ S_part,
                                              const float* __restrict__ S_old,
                                              float* __restrict__ S_new,
                                              int npart) {
    const int c = blockIdx.x;
    const int d = threadIdx.x;
    if (d < c) return;   // upper triangle incl diagonal
    const int t = (c >> 7) + (d >> 7);
    const int r = c & 127, col = d & 127;
    const float* base = S_part + (size_t)t * 16384 + (size_t)r * 128 + col;
    double s0 = 0.0, s1 = 0.0;
    int p = 0;
    for (; p + 1 < npart; p += 2) {
        s0 += (double)base[(size_t)p * 49152];
        s1 += (double)base[(size_t)(p + 1) * 49152];
    }
    for (; p < npart; ++p) s0 += (double)base[(size_t)p * 49152];
    const float sb = (float)((s0 + s1) * (1.0 / 32.0));   // mean over B=32
    S_new[c * 256 + d] = 0.999f * S_old[c * 256 + d] + 0.001f * sb;
    if (d != c)
        S_new[d * 256 + c] = 0.999f * S_old[d * 256 + c] + 0.001f * sb;
}

// ---------------------------------------------------------------------------
// Kernel 4: per-sample mask + permutation (unchanged).
// ---------------------------------------------------------------------------
__global__ __launch_bounds__(256) void k_perm(const float* __restrict__ s_score,
                                              const float* __restrict__ U,
                                              const float* __restrict__ S_new,
                                              int* __restrict__ perm_g) {
    const int b = blockIdx.x;
    const int c = threadIdx.x;
    __shared__ float red[256];
    __shared__ int m[256];
    __shared__ int jj[256];
    __shared__ int perm[256];

    const float s = s_score[b * 256 + c];
    red[c] = s; __syncthreads();
    for (int off = 128; off > 0; off >>= 1) {
        if (c < off) red[c] = fmaxf(red[c], red[c + off]);
        __syncthreads();
    }
    const float smax = red[0];
    __syncthreads();

    const float prob = 1.f / (1.f + expf(-5.f * (s - 0.6f * smax)));
    const int mi = (U[b * 256 + c] < prob) ? 1 : 0;
    m[c] = mi;
    red[c] = (float)mi;
    __syncthreads();
    for (int off = 128; off > 0; off >>= 1) {
        if (c < off) red[c] += red[c + off];
        __syncthreads();
    }
    const int cnt = (int)red[0];

    float best = -INFINITY; int bj = 0;
    const float* row = S_new + c * 256;
    for (int d2 = 0; d2 < 256; ++d2) {
        const float v = row[d2];
        if (!m[d2] && v > best) { best = v; bj = d2; }
    }
    jj[c] = bj;
    perm[c] = mi ? bj : c;
    __syncthreads();

    const int valid = (cnt > 0) && (cnt < 256);
    if (c == 0 && valid) {
        for (int q = 0; q < 256; ++q)
            if (m[q]) perm[jj[q]] = q;      // last-wins, ascending q
    }
    __syncthreads();
    perm_g[b * 256 + c] = valid ? perm[c] : c;
}

// ---------------------------------------------------------------------------
// Kernel 5: gather planes (unchanged).
// ---------------------------------------------------------------------------
__global__ __launch_bounds__(256) void k_gather(const float* __restrict__ F,
                                                const int* __restrict__ perm_g,
                                                float* __restrict__ out) {
    const int plane = blockIdx.x;            // b*256 + c
    const int b = plane >> 8;
    const int p = perm_g[plane];
    const float4* src = (const float4*)(F + ((size_t)b * 256 + p) * NN);
    float4* dst = (float4*)(out + (size_t)plane * NN);
    const int tid = threadIdx.x;
    #pragma unroll
    for (int q = 0; q < 4; ++q) dst[tid + q * 256] = src[tid + q * 256];
}

// ---------------------------------------------------------------------------
extern "C" void kernel_launch(void* const* d_in, const int* in_sizes, int n_in,
                              void* d_out, int out_size, void* d_ws, size_t ws_size,
                              hipStream_t stream) {
    const float* F = (const float*)d_in[0];
    const float* S = (const float*)d_in[1];
    const float* U = (const float*)d_in[2];
    float* out = (float*)d_out;

    // split-K ladder: nch=8 -> 50.4 MB partials (grid 768 = 3/CU, balanced);
    // fall back to 4 (25.2 MB) or 2 (12.6 MB) if ws is small.
    const size_t extras = (size_t)(3 * 8192 + 65536) * 4 + 65536;
    int csh = 1;
    if (ws_size >= (size_t)(32 << 3) * 3 * 16384 * 4 + extras) csh = 3;
    else if (ws_size >= (size_t)(32 << 2) * 3 * 16384 * 4 + extras) csh = 2;
    const int npart = 32 << csh;

    char* ws = (char*)d_ws;
    size_t off = 0;
    float* S_part  = (float*)(ws + off); off += (size_t)npart * 3 * 16384 * 4;
    float* inv_nrm = (float*)(ws + off); off += 8192 * 4;
    float* s_score = (float*)(ws + off); off += 8192 * 4;
    float* S_new   = (float*)(ws + off); off += 65536 * 4;
    int*   perm    = (int*)  (ws + off); off += 8192 * 4;

    k_prep  <<<8192, 256, 0, stream>>>(F, inv_nrm, s_score);
    k_gram  <<<dim3(3, npart), 256, 0, stream>>>(F, inv_nrm, S_part, csh);
    k_snew  <<<256, 256, 0, stream>>>(S_part, S, S_new, npart);
    k_perm  <<<32, 256, 0, stream>>>(s_score, U, S_new, perm);
    k_gather<<<8192, 256, 0, stream>>>(F, perm, out);
}

// Round 6
// 449.034 us; speedup vs baseline: 1.1524x; 1.1524x over previous
//
#include <hip/hip_runtime.h>
#include <math.h>

// Problem constants
#define BB 32
#define CC 256
#define HH 64
#define WW 64
#define NN 4096   // H*W

__inline__ __device__ float waveReduceSum(float v) {
    #pragma unroll
    for (int off = 32; off > 0; off >>= 1) v += __shfl_xor(v, off);
    return v;
}
__inline__ __device__ float waveReduceMax(float v) {
    #pragma unroll
    for (int off = 32; off > 0; off >>= 1) v = fmaxf(v, __shfl_xor(v, off));
    return v;
}

// ---------------------------------------------------------------------------
// Kernel 1 (v2): per-(b,c) plane prep. Pooling via wave-ballot bitmasks:
//   row mask (64 bits) = __ballot(F(row, lane) >= thr)  [wave-uniform row]
//   horizontal 5-count = popcount of 5-bit window of the row mask
//   vertical 5-sum     = register ring over 20 halo rows per wave
// Integer-exact: identical counts to the float avg-pool (>=0.5 <=> cnt>=13).
// ---------------------------------------------------------------------------
__global__ __launch_bounds__(256) void k_prep(const float* __restrict__ F,
                                              float* __restrict__ inv_norm,
                                              float* __restrict__ s_score) {
    const int plane = blockIdx.x;                 // b*256 + c
    const int tid = threadIdx.x;
    __shared__ float fpl[4096];                   // raw plane copy
    __shared__ float swS[4], swQ[4], swM[4];

    const float4* src = (const float4*)(F + (size_t)plane * NN);
    float4 v[4];
    float sum = 0.f, ssq = 0.f, mx = -INFINITY;
    #pragma unroll
    for (int q = 0; q < 4; ++q) {
        v[q] = src[tid + q * 256];
        *(float4*)&fpl[(tid + q * 256) * 4] = v[q];
        sum += v[q].x + v[q].y + v[q].z + v[q].w;
        ssq += v[q].x * v[q].x + v[q].y * v[q].y + v[q].z * v[q].z + v[q].w * v[q].w;
        mx = fmaxf(mx, fmaxf(fmaxf(v[q].x, v[q].y), fmaxf(v[q].z, v[q].w)));
    }
    sum = waveReduceSum(sum);
    ssq = waveReduceSum(ssq);
    mx  = waveReduceMax(mx);
    const int w = tid >> 6, lane = tid & 63;
    if (lane == 0) { swS[w] = sum; swQ[w] = ssq; swM[w] = mx; }
    __syncthreads();
    if (tid == 0) {
        swS[0] = swS[0] + swS[1] + swS[2] + swS[3];
        swQ[0] = swQ[0] + swQ[1] + swQ[2] + swQ[3];
        swM[0] = fmaxf(fmaxf(swM[0], swM[1]), fmaxf(swM[2], swM[3]));
    }
    __syncthreads();
    const float totsum = swS[0];
    const float totssq = swQ[0];
    const float thr = 0.6f * swM[0];
    __syncthreads();   // swS reused below

    // wave w owns output rows [16w, 16w+16); halo rows [16w-2, 16w+18)
    int hh[20];
    #pragma unroll
    for (int j = 0; j < 20; ++j) {
        const int row = 16 * w - 2 + j;
        unsigned long long m = 0ull;
        if (row >= 0 && row < 64) {                       // wave-uniform branch
            m = __ballot(fpl[row * 64 + lane] >= thr);
        }
        const unsigned long long sh =
            (lane >= 2) ? (m >> (lane - 2)) : (m << (2 - lane));
        hh[j] = (int)__popcll(sh & 31ull);
    }
    int cge = 0;
    #pragma unroll
    for (int r = 0; r < 16; ++r) {
        const int c5 = hh[r] + hh[r + 1] + hh[r + 2] + hh[r + 3] + hh[r + 4];
        cge += (c5 >= 13) ? 1 : 0;   // density >= 0.5 exactly (integer counts)
    }
    float cf = waveReduceSum((float)cge);
    if (lane == 0) swS[w] = cf;
    __syncthreads();
    if (tid == 0) {
        const float total = swS[0] + swS[1] + swS[2] + swS[3];
        const float d = total / 4096.f;
        const float a = 1.f / (1.f + expf(-(totsum / 4096.f)));
        s_score[plane] = sqrtf(a) * sqrtf(d);
        inv_norm[plane] = 1.f / (sqrtf(totssq) + 1e-6f);
    }
}

// ---------------------------------------------------------------------------
// Kernel 2 (v3): gram partials. R3 64x64 structure + split-K x8 + swizzle.
// 10 sym tiles; grid (10, 32*nch) = 2560 blocks = 10/CU at nch=8.
// LDS layout [kk][col] stride 68 with COLUMN ROTATION:
//   col_phys(row, kk) = (row + 16*((kk>>3)&1)) & 63
// Staging-write banks: (4j + lrow + 16*(kgrp&1))%32 -> exactly 2-way (free).
// Reads stay b128-contiguous & 16B-aligned (offset multiple of 16).
// Flat fp32 acc (K=512/partial, R4-proven); row-norm scaling at epilogue.
// Output: S_part[bc*10 + t][64][64], bc in [0, 32*nch).
// ---------------------------------------------------------------------------
__global__ __launch_bounds__(256) void k_gram(const float* __restrict__ F,
                                              const float* __restrict__ inv_norm,
                                              float* __restrict__ S_part,
                                              int csh) {
    static const int TI[10] = {0,0,0,0,1,1,1,2,2,3};
    static const int TJ[10] = {0,1,2,3,1,2,3,2,3,3};
    const int t  = blockIdx.x;       // 0..9 tile
    const int bc = blockIdx.y;       // 0..32*nch-1
    const int b = bc >> csh, chunk = bc & ((1 << csh) - 1);
    const int ti = TI[t], tj = TJ[t];
    const int k0 = chunk << (12 - csh);          // chunk * (4096>>csh)
    const int iters = (4096 >> csh) >> 5;        // K-chunk / 32

    __shared__ float As[32][68];
    __shared__ float Bs[32][68];

    const int tid = threadIdx.x;
    const int lrow = tid >> 2;       // 0..63 logical row
    const int kgrp = tid & 3;        // 0..3 (8 k-values each)
    const float* Fb = F + (size_t)b * CC * NN;
    const float* gA = Fb + (size_t)(ti * 64 + lrow) * NN + k0 + kgrp * 8;
    const float* gB = Fb + (size_t)(tj * 64 + lrow) * NN + k0 + kgrp * 8;

    // column rotation for this thread's writes: kk = kgrp*8+j -> (kk>>3)&1 = kgrp&1
    const int colW = (lrow + ((kgrp & 1) << 4)) & 63;
    const int kb = kgrp * 8;

    const int r0 = (tid >> 4) << 2;  // row quad 0..60
    const int c0 = (tid & 15) << 2;  // col quad 0..60

    float acc[16];
    #pragma unroll
    for (int e = 0; e < 16; ++e) acc[e] = 0.f;

    for (int s = 0; s < iters; ++s) {
        const float4 a0 = *(const float4*)(gA);
        const float4 a1 = *(const float4*)(gA + 4);
        const float4 b0 = *(const float4*)(gB);
        const float4 b1 = *(const float4*)(gB + 4);
        __syncthreads();
        {
            const float va[8] = {a0.x,a0.y,a0.z,a0.w,a1.x,a1.y,a1.z,a1.w};
            const float vb[8] = {b0.x,b0.y,b0.z,b0.w,b1.x,b1.y,b1.z,b1.w};
            #pragma unroll
            for (int j = 0; j < 8; ++j) {
                As[kb + j][colW] = va[j];
                Bs[kb + j][colW] = vb[j];
            }
        }
        __syncthreads();

        #pragma unroll
        for (int kk = 0; kk < 32; ++kk) {
            const int off = ((kk >> 3) & 1) << 4;
            const float4 av = *(const float4*)&As[kk][(r0 + off) & 63];
            const float4 bv = *(const float4*)&Bs[kk][(c0 + off) & 63];
            const float ar[4] = {av.x, av.y, av.z, av.w};
            const float br[4] = {bv.x, bv.y, bv.z, bv.w};
            #pragma unroll
            for (int rr = 0; rr < 4; ++rr)
                #pragma unroll
                for (int cc = 0; cc < 4; ++cc)
                    acc[rr * 4 + cc] = fmaf(ar[rr], br[cc], acc[rr * 4 + cc]);
        }
        gA += 32; gB += 32;
    }

    // epilogue: scale by row norms (exact product scaling), store
    const float* invA = inv_norm + b * CC + ti * 64;
    const float* invB = inv_norm + b * CC + tj * 64;
    float sA[4], sB[4];
    #pragma unroll
    for (int e = 0; e < 4; ++e) { sA[e] = invA[r0 + e]; sB[e] = invB[c0 + e]; }
    float* dst = S_part + (size_t)(bc * 10 + t) * 4096;
    #pragma unroll
    for (int rr = 0; rr < 4; ++rr)
        #pragma unroll
        for (int cc = 0; cc < 4; ++cc)
            dst[(r0 + rr) * 64 + (c0 + cc)] = acc[rr * 4 + cc] * sA[rr] * sB[cc];
}

// ---------------------------------------------------------------------------
// Kernel 3: reduce npart partials (f64, deterministic), EMA, symmetrize.
// ---------------------------------------------------------------------------
__global__ __launch_bounds__(256) void k_snew(const float* __restrict__ S_part,
                                              const float* __restrict__ S_old,
                                              float* __restrict__ S_new,
                                              int npart) {
    const int c = blockIdx.x;
    const int d = threadIdx.x;
    if (d < c) return;   // upper triangle incl diagonal
    static const int tmap[16] = {0,1,2,3, -1,4,5,6, -1,-1,7,8, -1,-1,-1,9};
    const int t = tmap[((c >> 6) << 2) | (d >> 6)];
    const int r = c & 63, col = d & 63;
    const float* base = S_part + (size_t)t * 4096 + r * 64 + col;
    double s0 = 0.0, s1 = 0.0;
    int p = 0;
    for (; p + 1 < npart; p += 2) {
        s0 += (double)base[(size_t)p * 40960];
        s1 += (double)base[(size_t)(p + 1) * 40960];
    }
    for (; p < npart; ++p) s0 += (double)base[(size_t)p * 40960];
    const float sb = (float)((s0 + s1) * (1.0 / 32.0));   // mean over B=32
    S_new[c * 256 + d] = 0.999f * S_old[c * 256 + d] + 0.001f * sb;
    if (d != c)
        S_new[d * 256 + c] = 0.999f * S_old[d * 256 + c] + 0.001f * sb;
}

// ---------------------------------------------------------------------------
// Kernel 4: per-sample mask + permutation (unchanged — exact 3 rounds).
// ---------------------------------------------------------------------------
__global__ __launch_bounds__(256) void k_perm(const float* __restrict__ s_score,
                                              const float* __restrict__ U,
                                              const float* __restrict__ S_new,
                                              int* __restrict__ perm_g) {
    const int b = blockIdx.x;
    const int c = threadIdx.x;
    __shared__ float red[256];
    __shared__ int m[256];
    __shared__ int jj[256];
    __shared__ int perm[256];

    const float s = s_score[b * 256 + c];
    red[c] = s; __syncthreads();
    for (int off = 128; off > 0; off >>= 1) {
        if (c < off) red[c] = fmaxf(red[c], red[c + off]);
        __syncthreads();
    }
    const float smax = red[0];
    __syncthreads();

    const float prob = 1.f / (1.f + expf(-5.f * (s - 0.6f * smax)));
    const int mi = (U[b * 256 + c] < prob) ? 1 : 0;
    m[c] = mi;
    red[c] = (float)mi;
    __syncthreads();
    for (int off = 128; off > 0; off >>= 1) {
        if (c < off) red[c] += red[c + off];
        __syncthreads();
    }
    const int cnt = (int)red[0];

    float best = -INFINITY; int bj = 0;
    const float* row = S_new + c * 256;
    for (int d2 = 0; d2 < 256; ++d2) {
        const float v = row[d2];
        if (!m[d2] && v > best) { best = v; bj = d2; }
    }
    jj[c] = bj;
    perm[c] = mi ? bj : c;
    __syncthreads();

    const int valid = (cnt > 0) && (cnt < 256);
    if (c == 0 && valid) {
        for (int q = 0; q < 256; ++q)
            if (m[q]) perm[jj[q]] = q;      // last-wins, ascending q
    }
    __syncthreads();
    perm_g[b * 256 + c] = valid ? perm[c] : c;
}

// ---------------------------------------------------------------------------
// Kernel 5: gather planes (unchanged).
// ---------------------------------------------------------------------------
__global__ __launch_bounds__(256) void k_gather(const float* __restrict__ F,
                                                const int* __restrict__ perm_g,
                                                float* __restrict__ out) {
    const int plane = blockIdx.x;            // b*256 + c
    const int b = plane >> 8;
    const int p = perm_g[plane];
    const float4* src = (const float4*)(F + ((size_t)b * 256 + p) * NN);
    float4* dst = (float4*)(out + (size_t)plane * NN);
    const int tid = threadIdx.x;
    #pragma unroll
    for (int q = 0; q < 4; ++q) dst[tid + q * 256] = src[tid + q * 256];
}

// ---------------------------------------------------------------------------
extern "C" void kernel_launch(void* const* d_in, const int* in_sizes, int n_in,
                              void* d_out, int out_size, void* d_ws, size_t ws_size,
                              hipStream_t stream) {
    const float* F = (const float*)d_in[0];
    const float* S = (const float*)d_in[1];
    const float* U = (const float*)d_in[2];
    float* out = (float*)d_out;

    // split-K ladder: nch=8 -> 41.9 MB partials (grid 2560 = 10/CU);
    // fall back to 4 (21 MB) or 2 (10.5 MB) if ws is small.
    const size_t extras = (size_t)(3 * 8192 + 65536) * 4 + 65536;
    int csh = 1;
    if (ws_size >= (size_t)(32 << 3) * 10 * 4096 * 4 + extras) csh = 3;
    else if (ws_size >= (size_t)(32 << 2) * 10 * 4096 * 4 + extras) csh = 2;
    const int npart = 32 << csh;

    char* ws = (char*)d_ws;
    size_t off = 0;
    float* S_part  = (float*)(ws + off); off += (size_t)npart * 10 * 4096 * 4;
    float* inv_nrm = (float*)(ws + off); off += 8192 * 4;
    float* s_score = (float*)(ws + off); off += 8192 * 4;
    float* S_new   = (float*)(ws + off); off += 65536 * 4;
    int*   perm    = (int*)  (ws + off); off += 8192 * 4;

    k_prep  <<<8192, 256, 0, stream>>>(F, inv_nrm, s_score);
    k_gram  <<<dim3(10, npart), 256, 0, stream>>>(F, inv_nrm, S_part, csh);
    k_snew  <<<256, 256, 0, stream>>>(S_part, S, S_new, npart);
    k_perm  <<<32, 256, 0, stream>>>(s_score, U, S_new, perm);
    k_gather<<<8192, 256, 0, stream>>>(F, perm, out);
}